// Round 1
// baseline (775.592 us; speedup 1.0000x reference)
//
#include <hip/hip_runtime.h>
#include <hip/hip_bf16.h>
#include <stdint.h>

typedef unsigned short u16;
typedef u16   u16x8 __attribute__((ext_vector_type(8)));
typedef short s16x8 __attribute__((ext_vector_type(8)));
typedef float f32x4 __attribute__((ext_vector_type(4)));

#define TOKENS 51200
#define DMODEL 1024
#define DINNER 2048
#define NSTATE 16
#define SEQLEN 100

// workspace layout (bytes)
#define OFF_XP    0ull          // 51200*1024*2   = 104857600
#define OFF_WCAT  104857600ull  // 4096*1024*2    =   8388608
#define OFF_WB    113246208ull  // 16*2048*2      =     65536
#define OFF_WC    113311744ull  // 16*1024*2      =     32768
#define OFF_BPART 113344512ull  // 16*51200*16*4  =  52428800
#define OFF_BFIN  165773312ull  // 51200*16*4     =   3276800
#define OFF_CBUF  169050112ull  // 51200*16*4
#define OFF_Y     172326912ull  // 51200*16*4     -> total 175603712 bytes

__device__ __forceinline__ u16 f2b(float f) {  // f32 -> bf16 RNE
  uint32_t u = __float_as_uint(f);
  uint32_t r = (u + 0x7fffu + ((u >> 16) & 1u)) >> 16;
  return (u16)r;
}
__device__ __forceinline__ float b2f(u16 u) {
  return __uint_as_float(((uint32_t)u) << 16);
}

#define GLL(gp, lp) __builtin_amdgcn_global_load_lds( \
    (__attribute__((address_space(1))) unsigned int*)(gp), \
    (__attribute__((address_space(3))) unsigned int*)(lp), 16, 0, 0)

// ---------------- prep: XP = bf16(x + pos_emb) ----------------
__global__ void k_prep_x(const float* __restrict__ x, const float* __restrict__ pos,
                         u16* __restrict__ xp) {
  long e = ((long)blockIdx.x * blockDim.x + threadIdx.x) * 8;  // < 52428800
  int d = (int)(e & (DMODEL - 1));
  long tok = e >> 10;
  int s = (int)(tok % SEQLEN);
  f32x4 a0 = *(const f32x4*)(x + e);
  f32x4 a1 = *(const f32x4*)(x + e + 4);
  f32x4 p0 = *(const f32x4*)(pos + (size_t)s * DMODEL + d);
  f32x4 p1 = *(const f32x4*)(pos + (size_t)s * DMODEL + d + 4);
  u16x8 o;
  o[0] = f2b(a0[0] + p0[0]); o[1] = f2b(a0[1] + p0[1]);
  o[2] = f2b(a0[2] + p0[2]); o[3] = f2b(a0[3] + p0[3]);
  o[4] = f2b(a1[0] + p1[0]); o[5] = f2b(a1[1] + p1[1]);
  o[6] = f2b(a1[2] + p1[2]); o[7] = f2b(a1[3] + p1[3]);
  *(u16x8*)(xp + e) = o;
}

// ---------------- prep: Wcat = bf16([W_in; W_gate]) ----------------
__global__ void k_prep_w(const float* __restrict__ Win, const float* __restrict__ Wg,
                         u16* __restrict__ wcat) {
  long e = ((long)blockIdx.x * blockDim.x + threadIdx.x) * 8;  // < 4194304
  const float* src = (e < 2097152) ? (Win + e) : (Wg + (e - 2097152));
  f32x4 a0 = *(const f32x4*)src;
  f32x4 a1 = *(const f32x4*)(src + 4);
  u16x8 o;
  o[0] = f2b(a0[0]); o[1] = f2b(a0[1]); o[2] = f2b(a0[2]); o[3] = f2b(a0[3]);
  o[4] = f2b(a1[0]); o[5] = f2b(a1[1]); o[6] = f2b(a1[2]); o[7] = f2b(a1[3]);
  *(u16x8*)(wcat + e) = o;
}

// ---------------- prep: W_B, W_C -> bf16 ----------------
__global__ void k_prep_wbc(const float* __restrict__ WB, const float* __restrict__ WC,
                           u16* __restrict__ wb, u16* __restrict__ wc) {
  long e = ((long)blockIdx.x * blockDim.x + threadIdx.x) * 8;  // < 49152
  const float* src; u16* dst;
  if (e < 32768) { src = WB + e; dst = wb + e; }
  else           { src = WC + (e - 32768); dst = wc + (e - 32768); }
  f32x4 a0 = *(const f32x4*)src;
  f32x4 a1 = *(const f32x4*)(src + 4);
  u16x8 o;
  o[0] = f2b(a0[0]); o[1] = f2b(a0[1]); o[2] = f2b(a0[2]); o[3] = f2b(a0[3]);
  o[4] = f2b(a1[0]); o[5] = f2b(a1[1]); o[6] = f2b(a1[2]); o[7] = f2b(a1[3]);
  *(u16x8*)(dst) = o;
}

// ---------------- fused dual GEMM + gate + B-projection ----------------
// block: 128 rows x 128 cols (of BOTH proj and gate), 512 threads (8 waves, 2x4)
// K = 1024, BK = 32, double-buffered LDS via global_load_lds (m97 structure).
__global__ __launch_bounds__(512) void k_gemm(
    const u16* __restrict__ XP, const u16* __restrict__ WCAT, const u16* __restrict__ WBb,
    const float* __restrict__ b_in, const float* __restrict__ b_gate,
    float* __restrict__ Bpart) {
  __shared__ __align__(16) u16 smem[2][3][4096];  // [buf][A,Wp,Wg][128*32]

  const int tid = threadIdx.x;
  const int bid = blockIdx.x;
  // XCD-affine swizzle: XCD x owns col-chunks {2x, 2x+1} -> its 1MB of weights stays L2-resident
  const int cb = ((bid & 7) << 1) | ((bid >> 3) & 1);  // 0..15
  const int rb = bid >> 4;                             // 0..399
  const int m0 = rb << 7;
  const int c0 = cb << 7;

  const int srow = tid >> 2;          // 0..127
  const int sko  = (tid & 3) << 3;    // 0,8,16,24
  const u16* gA  = XP   + (size_t)(m0 + srow) * DMODEL + sko;
  const u16* gBp = WCAT + (size_t)(c0 + srow) * DMODEL + sko;
  const u16* gBg = WCAT + (size_t)(DINNER + c0 + srow) * DMODEL + sko;

  const int wid = tid >> 6, lane = tid & 63;
  const int wm = wid >> 2, wn = wid & 3;     // 2 x 4 wave grid
  const int l15 = lane & 15, lhi = lane >> 4;
  const int aoff = ((wm << 6) + l15) * 32 + (lhi << 3);
  const int boff = ((wn << 5) + l15) * 32 + (lhi << 3);

  f32x4 accp[4][2] = {};
  f32x4 accg[4][2] = {};

  auto stage = [&](int buf, int t) {
    const int kt = t << 5;
    GLL(gA  + kt, &smem[buf][0][tid << 3]);
    GLL(gBp + kt, &smem[buf][1][tid << 3]);
    GLL(gBg + kt, &smem[buf][2][tid << 3]);
  };
  auto compute = [&](int buf) {
    const u16* As = smem[buf][0];
    const u16* Ps = smem[buf][1];
    const u16* Gs = smem[buf][2];
    s16x8 a[4], p[2], g[2];
#pragma unroll
    for (int mi = 0; mi < 4; ++mi) a[mi] = *(const s16x8*)(As + aoff + mi * 512);
#pragma unroll
    for (int ni = 0; ni < 2; ++ni) {
      p[ni] = *(const s16x8*)(Ps + boff + ni * 512);
      g[ni] = *(const s16x8*)(Gs + boff + ni * 512);
    }
#pragma unroll
    for (int mi = 0; mi < 4; ++mi)
#pragma unroll
      for (int ni = 0; ni < 2; ++ni) {
        accp[mi][ni] = __builtin_amdgcn_mfma_f32_16x16x32_bf16(a[mi], p[ni], accp[mi][ni], 0, 0, 0);
        accg[mi][ni] = __builtin_amdgcn_mfma_f32_16x16x32_bf16(a[mi], g[ni], accg[mi][ni], 0, 0, 0);
      }
  };

  stage(0, 0);
  __syncthreads();
  int cur = 0;
  for (int t = 0; t < 31; ++t) {
    stage(cur ^ 1, t + 1);   // prefetch next K-tile; latency hides under MFMA
    compute(cur);
    __syncthreads();         // compiler emits vmcnt(0) lgkmcnt(0) drain here
    cur ^= 1;
  }
  compute(cur);
  __syncthreads();

  // epilogue: xg = (proj + b_in) * sigmoid(gate + b_gate), bf16 -> LDS [128][136] (pad: 2-way banks)
  u16* xg = &smem[0][0][0];  // 128*136*2 = 34816 B <= 49152 B
#pragma unroll
  for (int ni = 0; ni < 2; ++ni) {
    const int colL = (wn << 5) + (ni << 4) + l15;
    const float bi = b_in[c0 + colL];
    const float bg = b_gate[c0 + colL];
#pragma unroll
    for (int mi = 0; mi < 4; ++mi)
#pragma unroll
      for (int j = 0; j < 4; ++j) {
        const int row = (wm << 6) + (mi << 4) + (lhi << 2) + j;
        float pv = accp[mi][ni][j] + bi;
        float gv = accg[mi][ni][j] + bg;
        float v = pv / (1.0f + __expf(-gv));
        xg[row * 136 + colL] = f2b(v);
      }
  }
  __syncthreads();

  // mini-GEMM: Bpart[cb][row][n] = sum_{c in chunk} xg[row][c] * W_B[n][c0+c]
  // wave w owns rows w*16..w*16+15; M=128, N=16, K=128 -> 4 MFMAs/wave
  f32x4 bacc = {0.f, 0.f, 0.f, 0.f};
#pragma unroll
  for (int kc = 0; kc < 4; ++kc) {
    s16x8 av = *(const s16x8*)(xg + ((wid << 4) + l15) * 136 + (kc << 5) + (lhi << 3));
    s16x8 bv = *(const s16x8*)(WBb + (size_t)l15 * DINNER + c0 + (kc << 5) + (lhi << 3));
    bacc = __builtin_amdgcn_mfma_f32_16x16x32_bf16(av, bv, bacc, 0, 0, 0);
  }
  float* outp = Bpart + (((size_t)cb * TOKENS) + m0 + (wid << 4) + (lhi << 2)) * NSTATE + l15;
#pragma unroll
  for (int j = 0; j < 4; ++j) outp[j * NSTATE] = bacc[j];
}

// ---------------- C = XP @ W_C^T + b_C (one wave per token row) ----------------
__global__ void k_C(const u16* __restrict__ XP, const u16* __restrict__ WC,
                    const float* __restrict__ bC, float* __restrict__ Cb) {
  const int lane = threadIdx.x & 63;
  const int row = blockIdx.x * (blockDim.x >> 6) + (threadIdx.x >> 6);
  const u16* xr = XP + (size_t)row * DMODEL + (lane << 4);
  s16x8 x0 = *(const s16x8*)xr;
  s16x8 x1 = *(const s16x8*)(xr + 8);
  float xf[16];
#pragma unroll
  for (int u = 0; u < 8; ++u) { xf[u] = b2f((u16)x0[u]); xf[8 + u] = b2f((u16)x1[u]); }
  float acc[16];
#pragma unroll
  for (int n = 0; n < 16; ++n) {
    const u16* wr = WC + (size_t)n * DMODEL + (lane << 4);
    s16x8 w0 = *(const s16x8*)wr;
    s16x8 w1 = *(const s16x8*)(wr + 8);
    float s = 0.f;
#pragma unroll
    for (int u = 0; u < 8; ++u)
      s += xf[u] * b2f((u16)w0[u]) + xf[8 + u] * b2f((u16)w1[u]);
    acc[n] = s;
  }
#pragma unroll
  for (int n = 0; n < 16; ++n)
#pragma unroll
    for (int off = 32; off > 0; off >>= 1) acc[n] += __shfl_down(acc[n], off);
  if (lane == 0) {
    float* o = Cb + (size_t)row * NSTATE;
#pragma unroll
    for (int n = 0; n < 16; ++n) o[n] = acc[n] + bC[n];
  }
}

// ---------------- B = sum_chunks Bpart + b_B ----------------
__global__ void k_finB(const float* __restrict__ Bpart, const float* __restrict__ bB,
                       float* __restrict__ Bf) {
  const long i = (long)blockIdx.x * blockDim.x + threadIdx.x;  // per float4
  f32x4 s = {};
#pragma unroll
  for (int cb = 0; cb < 16; ++cb)
    s += *(const f32x4*)(Bpart + (size_t)cb * (TOKENS * NSTATE) + i * 4);
  s += *(const f32x4*)(bB + ((i & 3) << 2));
  *(f32x4*)(Bf + i * 4) = s;
}

// ---------------- sequential scan: h = A*h + B; y = h*C ----------------
__global__ void k_scan(const float* __restrict__ Bf, const float* __restrict__ Cb,
                       const float* __restrict__ Alog, float* __restrict__ Y) {
  const int t = threadIdx.x;
  const int b = blockIdx.x * 16 + (t >> 4);
  const int n = t & 15;
  const float A = __expf(0.01f * __expf(Alog[n]));
  float h = 0.f;
  const size_t base = (size_t)b * SEQLEN * NSTATE + n;
  for (int s = 0; s < SEQLEN; ++s) {
    const size_t idx = base + (size_t)s * NSTATE;
    h = A * h + Bf[idx];
    Y[idx] = h * Cb[idx];
  }
}

// ---------------- out = Y @ W_out[:, :16]^T + b_out ----------------
__global__ __launch_bounds__(256) void k_out(const float* __restrict__ Y,
                                             const float* __restrict__ Wout,
                                             const float* __restrict__ bout,
                                             float* __restrict__ out) {
  __shared__ float ys[32][16];
  const int tid = threadIdx.x;
  const long t0 = (long)blockIdx.x * 32;
  for (int i = tid; i < 512; i += 256) ys[i >> 4][i & 15] = Y[t0 * 16 + i];
  const int d0 = tid << 2;
  float w[4][16];
#pragma unroll
  for (int j = 0; j < 4; ++j)
#pragma unroll
    for (int q = 0; q < 4; ++q) {
      f32x4 wv = *(const f32x4*)(Wout + (size_t)(d0 + j) * DINNER + q * 4);
#pragma unroll
      for (int e = 0; e < 4; ++e) w[j][q * 4 + e] = wv[e];
    }
  f32x4 bo = *(const f32x4*)(bout + d0);
  __syncthreads();
  for (int r = 0; r < 32; ++r) {
    f32x4 acc = bo;
#pragma unroll
    for (int n = 0; n < 16; ++n) {
      const float yv = ys[r][n];
      acc[0] += yv * w[0][n];
      acc[1] += yv * w[1][n];
      acc[2] += yv * w[2][n];
      acc[3] += yv * w[3][n];
    }
    *(f32x4*)(out + (t0 + r) * 1024 + d0) = acc;
  }
}

extern "C" void kernel_launch(void* const* d_in, const int* in_sizes, int n_in,
                              void* d_out, int out_size, void* d_ws, size_t ws_size,
                              hipStream_t stream) {
  const float* x    = (const float*)d_in[0];
  const float* pos  = (const float*)d_in[1];
  const float* Win  = (const float*)d_in[2];
  const float* bin  = (const float*)d_in[3];
  const float* Wg   = (const float*)d_in[4];
  const float* bg   = (const float*)d_in[5];
  const float* Alog = (const float*)d_in[6];
  const float* WB   = (const float*)d_in[7];
  const float* bB   = (const float*)d_in[8];
  const float* WC   = (const float*)d_in[9];
  const float* bC   = (const float*)d_in[10];
  const float* Wout = (const float*)d_in[11];
  const float* bout = (const float*)d_in[12];

  char* ws = (char*)d_ws;
  u16*   XP   = (u16*)(ws + OFF_XP);
  u16*   WCAT = (u16*)(ws + OFF_WCAT);
  u16*   WBb  = (u16*)(ws + OFF_WB);
  u16*   WCb  = (u16*)(ws + OFF_WC);
  float* BP   = (float*)(ws + OFF_BPART);
  float* BF   = (float*)(ws + OFF_BFIN);
  float* CB   = (float*)(ws + OFF_CBUF);
  float* Yb   = (float*)(ws + OFF_Y);

  k_prep_x  <<<25600, 256, 0, stream>>>(x, pos, XP);
  k_prep_w  <<<2048, 256, 0, stream>>>(Win, Wg, WCAT);
  k_prep_wbc<<<24, 256, 0, stream>>>(WB, WC, WBb, WCb);
  k_gemm    <<<6400, 512, 0, stream>>>(XP, WCAT, WBb, bin, bg, BP);
  k_C       <<<12800, 256, 0, stream>>>(XP, WCb, bC, CB);
  k_finB    <<<800, 256, 0, stream>>>(BP, bB, BF);
  k_scan    <<<32, 256, 0, stream>>>(BF, CB, Alog, Yb);
  k_out     <<<1600, 256, 0, stream>>>(Yb, Wout, bout, (float*)d_out);
}

// Round 2
// 757.978 us; speedup vs baseline: 1.0232x; 1.0232x over previous
//
#include <hip/hip_runtime.h>
#include <hip/hip_bf16.h>
#include <stdint.h>

typedef unsigned short u16;
typedef u16   u16x8 __attribute__((ext_vector_type(8)));
typedef short s16x8 __attribute__((ext_vector_type(8)));
typedef float f32x4 __attribute__((ext_vector_type(4)));

#define TOKENS 51200
#define DMODEL 1024
#define DINNER 2048
#define NSTATE 16
#define SEQLEN 100

// workspace layout (bytes)
#define OFF_XP    0ull          // 51200*1024*2   = 104857600
#define OFF_WCAT  104857600ull  // 4096*1024*2    =   8388608
#define OFF_WB    113246208ull  // 16*2048*2      =     65536
#define OFF_WC    113311744ull  // 16*1024*2      =     32768
#define OFF_BPART 113344512ull  // 16*51200*16*4  =  52428800
#define OFF_BFIN  165773312ull  // 51200*16*4     =   3276800
#define OFF_CBUF  169050112ull  // 51200*16*4
#define OFF_Y     172326912ull  // 51200*16*4     -> total 175603712 bytes

__device__ __forceinline__ u16 f2b(float f) {  // f32 -> bf16 RNE
  uint32_t u = __float_as_uint(f);
  uint32_t r = (u + 0x7fffu + ((u >> 16) & 1u)) >> 16;
  return (u16)r;
}
__device__ __forceinline__ float b2f(u16 u) {
  return __uint_as_float(((uint32_t)u) << 16);
}

#define GLL(gp, lp) __builtin_amdgcn_global_load_lds( \
    (__attribute__((address_space(1))) unsigned int*)(gp), \
    (__attribute__((address_space(3))) unsigned int*)(lp), 16, 0, 0)

// ---------------- prep: XP = bf16(x + pos_emb) ----------------
__global__ void k_prep_x(const float* __restrict__ x, const float* __restrict__ pos,
                         u16* __restrict__ xp) {
  long e = ((long)blockIdx.x * blockDim.x + threadIdx.x) * 8;
  int d = (int)(e & (DMODEL - 1));
  long tok = e >> 10;
  int s = (int)(tok % SEQLEN);
  f32x4 a0 = *(const f32x4*)(x + e);
  f32x4 a1 = *(const f32x4*)(x + e + 4);
  f32x4 p0 = *(const f32x4*)(pos + (size_t)s * DMODEL + d);
  f32x4 p1 = *(const f32x4*)(pos + (size_t)s * DMODEL + d + 4);
  u16x8 o;
  o[0] = f2b(a0[0] + p0[0]); o[1] = f2b(a0[1] + p0[1]);
  o[2] = f2b(a0[2] + p0[2]); o[3] = f2b(a0[3] + p0[3]);
  o[4] = f2b(a1[0] + p1[0]); o[5] = f2b(a1[1] + p1[1]);
  o[6] = f2b(a1[2] + p1[2]); o[7] = f2b(a1[3] + p1[3]);
  *(u16x8*)(xp + e) = o;
}

// ---------------- prep: W2 = bf16 row-interleaved [Win;Wg] ----------------
// W2 row r (r = 32j+k): k<16 -> Win[16j+k], else Wg[16j+k-16].
// Combined output col g==W2 row g: even 16-group = proj, odd = gate.
__global__ void k_prep_w(const float* __restrict__ Win, const float* __restrict__ Wg,
                         u16* __restrict__ w2) {
  long e = ((long)blockIdx.x * blockDim.x + threadIdx.x) * 8;  // < 4194304
  int r = (int)(e >> 10), c = (int)(e & 1023);
  int srow = ((r >> 5) << 4) + (r & 15);
  const float* src = ((r & 16) ? Wg : Win) + (size_t)srow * DMODEL + c;
  f32x4 a0 = *(const f32x4*)src;
  f32x4 a1 = *(const f32x4*)(src + 4);
  u16x8 o;
  o[0] = f2b(a0[0]); o[1] = f2b(a0[1]); o[2] = f2b(a0[2]); o[3] = f2b(a0[3]);
  o[4] = f2b(a1[0]); o[5] = f2b(a1[1]); o[6] = f2b(a1[2]); o[7] = f2b(a1[3]);
  *(u16x8*)(w2 + e) = o;
}

// ---------------- prep: W_B, W_C -> bf16 ----------------
__global__ void k_prep_wbc(const float* __restrict__ WB, const float* __restrict__ WC,
                           u16* __restrict__ wb, u16* __restrict__ wc) {
  long e = ((long)blockIdx.x * blockDim.x + threadIdx.x) * 8;  // < 49152
  const float* src; u16* dst;
  if (e < 32768) { src = WB + e; dst = wb + e; }
  else           { src = WC + (e - 32768); dst = wc + (e - 32768); }
  f32x4 a0 = *(const f32x4*)src;
  f32x4 a1 = *(const f32x4*)(src + 4);
  u16x8 o;
  o[0] = f2b(a0[0]); o[1] = f2b(a0[1]); o[2] = f2b(a0[2]); o[3] = f2b(a0[3]);
  o[4] = f2b(a1[0]); o[5] = f2b(a1[1]); o[6] = f2b(a1[2]); o[7] = f2b(a1[3]);
  *(u16x8*)(dst) = o;
}

// ============ fused dual GEMM (256x256, BK=64, deep pipeline) ============
// 512 threads = 8 waves (2M x 4N). Per wave: 128 rows x 64 cols, acc[8][4].
// LDS: 2 bufs x (A 256x64 + B 256x64) bf16 = 131072 B (dynamic).
// Protocol per K-tile t: vmcnt(8); barrier; ds_read (swizzled); 32 MFMA;
// read hi frags; lgkmcnt(0); barrier; stage tile t+2; 32 MFMA.
__global__ __launch_bounds__(512, 2) void k_gemm256(
    const u16* __restrict__ XP, const u16* __restrict__ W2, const u16* __restrict__ WBb,
    const float* __restrict__ b_in, const float* __restrict__ b_gate,
    float* __restrict__ Bpart) {
  extern __shared__ __align__(16) u16 smem[];

  const int tid = threadIdx.x;
  const int bid = blockIdx.x;
  // XCD-affine swizzle: XCD owns nb pairs {2x,2x+1} -> 1 MB of W2 stays L2-resident
  const int nb = ((bid & 7) << 1) | ((bid >> 3) & 1);  // 0..15
  const int rb = bid >> 4;                             // 0..199
  const int m0 = rb << 8;
  const int n0 = nb << 8;

  // --- staging addresses (inverse-swizzled global source, linear LDS dest) ---
  const int arow  = tid >> 3;                              // 0..63 (row within 64-row round)
  const int acolsw = ((tid & 7) ^ (arow & 7)) << 3;        // element col after inv-swizzle
  const u16* gA = XP + (size_t)(m0 + arow) * DMODEL + acolsw;
  const u16* gB = W2 + (size_t)(n0 + arow) * DMODEL + acolsw;
  const int ldst = tid << 3;                               // u16 offset (16B/thread)

  // --- wave/frag constants ---
  const int wid = tid >> 6, lane = tid & 63;
  const int wm = wid >> 2, wn = wid & 3;
  const int l15 = lane & 15, lhi = lane >> 4;
  const int swz = (l15 & 7) << 4;                          // XOR swizzle (byte)
  const int arow0 = (wm << 7) + l15;                       // A row base (+ m*16)
  const int brow0 = (wn << 6) + l15;                       // B row base (+ n*16)
  const char* smemc = (const char*)smem;

  auto rdA = [&](int bufb, int m, int ks) -> s16x8 {
    return *(const s16x8*)(smemc + bufb + ((arow0 + (m << 4)) << 7) +
                           (((ks << 6) + (lhi << 4)) ^ swz));
  };
  auto rdB = [&](int bufb, int n, int ks) -> s16x8 {
    return *(const s16x8*)(smemc + bufb + 32768 + ((brow0 + (n << 4)) << 7) +
                           (((ks << 6) + (lhi << 4)) ^ swz));
  };
  auto STAGE = [&](int t) {
    const int bb = (t & 1) << 15;              // u16 offset of buffer
    const size_t go = (size_t)t << 6;          // t*64 in K
#pragma unroll
    for (int i = 0; i < 4; ++i)
      GLL(gA + go + ((size_t)i << 16), smem + bb + (i << 12) + ldst);
#pragma unroll
    for (int i = 0; i < 4; ++i)
      GLL(gB + go + ((size_t)i << 16), smem + bb + 16384 + (i << 12) + ldst);
  };

  f32x4 acc[8][4] = {};

  STAGE(0);
  STAGE(1);

#pragma unroll 1
  for (int t = 0; t < 16; ++t) {
    if (t == 15) asm volatile("s_waitcnt vmcnt(0)" ::: "memory");
    else         asm volatile("s_waitcnt vmcnt(8)" ::: "memory");
    asm volatile("s_barrier" ::: "memory");    // publish: everyone's tile-t loads done
    const int bufb = (t & 1) << 16;            // byte offset of buffer

    s16x8 bfr[4][2], afl[4][2], afh[4][2];
#pragma unroll
    for (int ks = 0; ks < 2; ++ks) {
#pragma unroll
      for (int n = 0; n < 4; ++n) bfr[n][ks] = rdB(bufb, n, ks);
#pragma unroll
      for (int m = 0; m < 4; ++m) afl[m][ks] = rdA(bufb, m, ks);
    }
    __builtin_amdgcn_s_setprio(1);
#pragma unroll
    for (int ks = 0; ks < 2; ++ks)
#pragma unroll
      for (int m = 0; m < 4; ++m)
#pragma unroll
        for (int n = 0; n < 4; ++n)
          acc[m][n] = __builtin_amdgcn_mfma_f32_16x16x32_bf16(afl[m][ks], bfr[n][ks], acc[m][n], 0, 0, 0);
    __builtin_amdgcn_s_setprio(0);
#pragma unroll
    for (int ks = 0; ks < 2; ++ks)
#pragma unroll
      for (int m = 0; m < 4; ++m) afh[m][ks] = rdA(bufb, m + 4, ks);
    asm volatile("s_waitcnt lgkmcnt(0)" ::: "memory");  // all reads of buf retired
    asm volatile("s_barrier" ::: "memory");             // -> safe to overwrite buf
    if (t < 14) STAGE(t + 2);
    __builtin_amdgcn_s_setprio(1);
#pragma unroll
    for (int ks = 0; ks < 2; ++ks)
#pragma unroll
      for (int m = 0; m < 4; ++m)
#pragma unroll
        for (int n = 0; n < 4; ++n)
          acc[m + 4][n] = __builtin_amdgcn_mfma_f32_16x16x32_bf16(afh[m][ks], bfr[n][ks], acc[m + 4][n], 0, 0, 0);
    __builtin_amdgcn_s_setprio(0);
  }

  // --- epilogue: in-register gating (acc[m][2u]=proj, acc[m][2u+1]=gate) ---
  u16* xg = smem;  // [256][136] bf16, +8 pad
  float bi[2], bg[2];
#pragma unroll
  for (int u = 0; u < 2; ++u) {
    const int gcol = (nb << 7) + (((wn << 1) + u) << 4) + l15;
    bi[u] = b_in[gcol];
    bg[u] = b_gate[gcol];
  }
#pragma unroll
  for (int m = 0; m < 8; ++m)
#pragma unroll
    for (int u = 0; u < 2; ++u)
#pragma unroll
      for (int j = 0; j < 4; ++j) {
        const int row = (wm << 7) + (m << 4) + (lhi << 2) + j;
        const int col = (((wn << 1) + u) << 4) + l15;
        float pv = acc[m][2 * u][j] + bi[u];
        float gv = acc[m][2 * u + 1][j] + bg[u];
        xg[row * 136 + col] = f2b(pv / (1.0f + __expf(-gv)));
      }
  asm volatile("s_waitcnt lgkmcnt(0)" ::: "memory");
  asm volatile("s_barrier" ::: "memory");

  // --- mini-GEMM: Bpart[nb][m0+row][state] = xg @ W_B[:, nb*128..+128]^T ---
  f32x4 bacc[2] = {};
#pragma unroll
  for (int m2 = 0; m2 < 2; ++m2)
#pragma unroll
    for (int kc = 0; kc < 4; ++kc) {
      s16x8 av = *(const s16x8*)(xg + ((wid << 5) + (m2 << 4) + l15) * 136 + (kc << 5) + (lhi << 3));
      s16x8 bv = *(const s16x8*)(WBb + (size_t)l15 * DINNER + (nb << 7) + (kc << 5) + (lhi << 3));
      bacc[m2] = __builtin_amdgcn_mfma_f32_16x16x32_bf16(av, bv, bacc[m2], 0, 0, 0);
    }
#pragma unroll
  for (int m2 = 0; m2 < 2; ++m2) {
    float* outp = Bpart + ((size_t)nb * TOKENS + m0 + (wid << 5) + (m2 << 4) + (lhi << 2)) * NSTATE + l15;
#pragma unroll
    for (int j = 0; j < 4; ++j) outp[j * NSTATE] = bacc[m2][j];
  }
}

// ---------------- C = XP @ W_C^T + b_C (one wave per token row) ----------------
__global__ void k_C(const u16* __restrict__ XP, const u16* __restrict__ WC,
                    const float* __restrict__ bC, float* __restrict__ Cb) {
  const int lane = threadIdx.x & 63;
  const int row = blockIdx.x * (blockDim.x >> 6) + (threadIdx.x >> 6);
  const u16* xr = XP + (size_t)row * DMODEL + (lane << 4);
  s16x8 x0 = *(const s16x8*)xr;
  s16x8 x1 = *(const s16x8*)(xr + 8);
  float xf[16];
#pragma unroll
  for (int u = 0; u < 8; ++u) { xf[u] = b2f((u16)x0[u]); xf[8 + u] = b2f((u16)x1[u]); }
  float acc[16];
#pragma unroll
  for (int n = 0; n < 16; ++n) {
    const u16* wr = WC + (size_t)n * DMODEL + (lane << 4);
    s16x8 w0 = *(const s16x8*)wr;
    s16x8 w1 = *(const s16x8*)(wr + 8);
    float s = 0.f;
#pragma unroll
    for (int u = 0; u < 8; ++u)
      s += xf[u] * b2f((u16)w0[u]) + xf[8 + u] * b2f((u16)w1[u]);
    acc[n] = s;
  }
#pragma unroll
  for (int n = 0; n < 16; ++n)
#pragma unroll
    for (int off = 32; off > 0; off >>= 1) acc[n] += __shfl_down(acc[n], off);
  if (lane == 0) {
    float* o = Cb + (size_t)row * NSTATE;
#pragma unroll
    for (int n = 0; n < 16; ++n) o[n] = acc[n] + bC[n];
  }
}

// ---------------- B = sum_chunks Bpart + b_B ----------------
__global__ void k_finB(const float* __restrict__ Bpart, const float* __restrict__ bB,
                       float* __restrict__ Bf) {
  const long i = (long)blockIdx.x * blockDim.x + threadIdx.x;  // per float4
  f32x4 s = {};
#pragma unroll
  for (int cb = 0; cb < 16; ++cb)
    s += *(const f32x4*)(Bpart + (size_t)cb * (TOKENS * NSTATE) + i * 4);
  s += *(const f32x4*)(bB + ((i & 3) << 2));
  *(f32x4*)(Bf + i * 4) = s;
}

// ---------------- sequential scan: h = A*h + B; y = h*C ----------------
__global__ void k_scan(const float* __restrict__ Bf, const float* __restrict__ Cb,
                       const float* __restrict__ Alog, float* __restrict__ Y) {
  const int t = threadIdx.x;
  const int b = blockIdx.x * 16 + (t >> 4);
  const int n = t & 15;
  const float A = __expf(0.01f * __expf(Alog[n]));
  float h = 0.f;
  const size_t base = (size_t)b * SEQLEN * NSTATE + n;
  for (int s = 0; s < SEQLEN; ++s) {
    const size_t idx = base + (size_t)s * NSTATE;
    h = A * h + Bf[idx];
    Y[idx] = h * Cb[idx];
  }
}

// ---------------- out = Y @ W_out[:, :16]^T + b_out ----------------
__global__ __launch_bounds__(256) void k_out(const float* __restrict__ Y,
                                             const float* __restrict__ Wout,
                                             const float* __restrict__ bout,
                                             float* __restrict__ out) {
  __shared__ float ys[32][16];
  const int tid = threadIdx.x;
  const long t0 = (long)blockIdx.x * 32;
  for (int i = tid; i < 512; i += 256) ys[i >> 4][i & 15] = Y[t0 * 16 + i];
  const int d0 = tid << 2;
  float w[4][16];
#pragma unroll
  for (int j = 0; j < 4; ++j)
#pragma unroll
    for (int q = 0; q < 4; ++q) {
      f32x4 wv = *(const f32x4*)(Wout + (size_t)(d0 + j) * DINNER + q * 4);
#pragma unroll
      for (int e = 0; e < 4; ++e) w[j][q * 4 + e] = wv[e];
    }
  f32x4 bo = *(const f32x4*)(bout + d0);
  __syncthreads();
  for (int r = 0; r < 32; ++r) {
    f32x4 acc = bo;
#pragma unroll
    for (int n = 0; n < 16; ++n) {
      const float yv = ys[r][n];
      acc[0] += yv * w[0][n];
      acc[1] += yv * w[1][n];
      acc[2] += yv * w[2][n];
      acc[3] += yv * w[3][n];
    }
    *(f32x4*)(out + (t0 + r) * 1024 + d0) = acc;
  }
}

extern "C" void kernel_launch(void* const* d_in, const int* in_sizes, int n_in,
                              void* d_out, int out_size, void* d_ws, size_t ws_size,
                              hipStream_t stream) {
  const float* x    = (const float*)d_in[0];
  const float* pos  = (const float*)d_in[1];
  const float* Win  = (const float*)d_in[2];
  const float* bin  = (const float*)d_in[3];
  const float* Wg   = (const float*)d_in[4];
  const float* bg   = (const float*)d_in[5];
  const float* Alog = (const float*)d_in[6];
  const float* WB   = (const float*)d_in[7];
  const float* bB   = (const float*)d_in[8];
  const float* WC   = (const float*)d_in[9];
  const float* bC   = (const float*)d_in[10];
  const float* Wout = (const float*)d_in[11];
  const float* bout = (const float*)d_in[12];

  char* ws = (char*)d_ws;
  u16*   XP   = (u16*)(ws + OFF_XP);
  u16*   W2   = (u16*)(ws + OFF_WCAT);
  u16*   WBb  = (u16*)(ws + OFF_WB);
  u16*   WCb  = (u16*)(ws + OFF_WC);
  float* BP   = (float*)(ws + OFF_BPART);
  float* BF   = (float*)(ws + OFF_BFIN);
  float* CB   = (float*)(ws + OFF_CBUF);
  float* Yb   = (float*)(ws + OFF_Y);

  hipFuncSetAttribute((const void*)k_gemm256,
                      hipFuncAttributeMaxDynamicSharedMemorySize, 131072);

  k_prep_x  <<<25600, 256, 0, stream>>>(x, pos, XP);
  k_prep_w  <<<2048, 256, 0, stream>>>(Win, Wg, W2);
  k_prep_wbc<<<24, 256, 0, stream>>>(WB, WC, WBb, WCb);
  k_gemm256 <<<3200, 512, 131072, stream>>>(XP, W2, WBb, bin, bg, BP);
  k_C       <<<12800, 256, 0, stream>>>(XP, WCb, bC, CB);
  k_finB    <<<800, 256, 0, stream>>>(BP, bB, BF);
  k_scan    <<<32, 256, 0, stream>>>(BF, CB, Alog, Yb);
  k_out     <<<1600, 256, 0, stream>>>(Yb, Wout, bout, (float*)d_out);
}